// Round 1
// baseline (6626.991 us; speedup 1.0000x reference)
//
#include <hip/hip_runtime.h>

#define BB 8
#define NN 4096
#define KK 20
constexpr float EPSV = 1e-5f;
constexpr float SLOPE = 0.2f;

__device__ __forceinline__ float lrelu(float v) { return v >= 0.f ? v : SLOPE * v; }

__global__ void zero_kernel(float* p, int n) {
    int i = blockIdx.x * 256 + threadIdx.x;
    if (i < n) p[i] = 0.f;
}

// ---------------- kNN: fused distance-tile + top-20 ----------------
// grid (N/64, B), block 256. Selection score s(n,m) = dot(n,m) - 0.5*||x_m||^2
// (monotone transform of reference d per row -> same top-k set).
template<int C>
__global__ void knn_kernel(const float* __restrict__ src, int* __restrict__ idx) {
    __shared__ __align__(16) float qf[C * 64];
    __shared__ __align__(16) float cf[C * 64];
    __shared__ float hn[64];
    __shared__ float sc[64 * 64];      // [m][q] layout (conflict-free merge reads)
    __shared__ float topv[64 * 20];
    __shared__ int   topi[64 * 20];

    const int b = blockIdx.y;
    const int q0 = blockIdx.x * 64;
    const int tid = threadIdx.x;

    for (int i = tid; i < 64 * 20; i += 256) topv[i] = -3.4e38f;
    for (int i = tid; i < C * 64; i += 256) {
        int c = i >> 6, q = i & 63;
        qf[i] = src[(b * C + c) * NN + q0 + q];
    }
    __syncthreads();

    const int qi = (tid & 15) * 4;
    const int mi = (tid >> 4) * 4;

    for (int ch = 0; ch < 64; ch++) {
        const int m0 = ch * 64;
        for (int i = tid; i < C * 64; i += 256) {
            int c = i >> 6, mm = i & 63;
            cf[i] = src[(b * C + c) * NN + m0 + mm];
        }
        __syncthreads();
        if (tid < 64) {
            float s = 0.f;
            for (int c = 0; c < C; c++) { float v = cf[c * 64 + tid]; s += v * v; }
            hn[tid] = 0.5f * s;
        }
        __syncthreads();

        float acc[4][4] = {};
        #pragma unroll 4
        for (int c = 0; c < C; c++) {
            const float4 qv = *(const float4*)(qf + c * 64 + qi);
            const float4 mv = *(const float4*)(cf + c * 64 + mi);
            float qa[4] = {qv.x, qv.y, qv.z, qv.w};
            float ma[4] = {mv.x, mv.y, mv.z, mv.w};
            #pragma unroll
            for (int i2 = 0; i2 < 4; i2++)
                #pragma unroll
                for (int j2 = 0; j2 < 4; j2++)
                    acc[i2][j2] += qa[i2] * ma[j2];
        }
        #pragma unroll
        for (int j2 = 0; j2 < 4; j2++) {
            float h = hn[mi + j2];
            #pragma unroll
            for (int i2 = 0; i2 < 4; i2++)
                sc[(mi + j2) * 64 + qi + i2] = acc[i2][j2] - h;
        }
        __syncthreads();

        if (tid < 64) {   // merge this chunk into query tid's top-20 (ascending list)
            const int q = tid;
            float* tv = &topv[q * 20];
            int*   ti = &topi[q * 20];
            for (int m = 0; m < 64; m++) {
                float v = sc[m * 64 + q];
                if (v > tv[0]) {
                    int j = 0;
                    while (j < 19 && tv[j + 1] < v) { tv[j] = tv[j + 1]; ti[j] = ti[j + 1]; j++; }
                    tv[j] = v; ti[j] = m0 + m;
                }
            }
        }
        __syncthreads();
    }

    if (tid < 64) {
        const int q = tid;
        for (int k = 0; k < KK; k++)
            idx[(b * NN + q0 + q) * KK + k] = topi[q * 20 + k];
    }
}

// ---------------- conv precompute: G = Wd*src, H = (Wc-Wd)*src ----------------
// grid (N/64, B), block (COUT, 256/COUT). G/H layout [b][m][o] (o contiguous).
template<int COUT>
__global__ void precompute_kernel(const float* __restrict__ src, int C,
                                  const float* __restrict__ w, int CIN, int wd_off, int wc_off,
                                  float* __restrict__ G, float* __restrict__ H,
                                  int initG, int initH) {
    constexpr int MY = 256 / COUT;
    extern __shared__ float lds[];           // wd[C*COUT], wc[C*COUT]
    float* wd = lds;
    float* wc = lds + C * COUT;
    const int b = blockIdx.y;
    const int tid = threadIdx.y * COUT + threadIdx.x;
    for (int i = tid; i < C * COUT; i += 256) {
        int c = i / COUT, o = i % COUT;
        float a  = w[o * CIN + wd_off + c];
        float cc = w[o * CIN + wc_off + c];
        wd[i] = a;
        wc[i] = cc - a;
    }
    __syncthreads();
    const int o = threadIdx.x;
    for (int it = 0; it < COUT / 4; it++) {
        int m = blockIdx.x * 64 + it * MY + threadIdx.y;
        float g = 0.f, h = 0.f;
        for (int c = 0; c < C; c++) {
            float s = src[(b * C + c) * NN + m];
            g += wd[c * COUT + o] * s;
            h += wc[c * COUT + o] * s;
        }
        int gi = (b * NN + m) * COUT + o;
        if (initG) G[gi] = g; else G[gi] += g;
        if (initH) H[gi] = h; else H[gi] += h;
    }
}

// ---------------- conv stats + per-(b,n,o) min/max over k ----------------
// y(b,n,k,o) = G1[idx1_k] (+ G2[idx2_k]) + H[n]. grid (N/NY, B), block (COUT,NY).
template<int COUT, int GROUPS>
__global__ void conv_stats_kernel(const float* __restrict__ G1, const int* __restrict__ idx1,
                                  const float* __restrict__ G2, const int* __restrict__ idx2,
                                  const float* __restrict__ H, float* __restrict__ stats,
                                  float* __restrict__ MaxY, float* __restrict__ MinY) {
    constexpr int NY = 256 / COUT;
    const int b = blockIdx.y;
    const int o = threadIdx.x;
    const int n = blockIdx.x * NY + threadIdx.y;
    const int base = b * NN + n;
    const float h = H[base * COUT + o];
    float s1 = 0.f, s2 = 0.f;
    float gx = -3.4e38f, gn = 3.4e38f;
    #pragma unroll
    for (int k = 0; k < KK; k++) {
        int i1 = idx1[base * KK + k];
        float g = G1[(b * NN + i1) * COUT + o];
        if (GROUPS == 2) {
            int i2 = idx2[base * KK + k];
            g += G2[(b * NN + i2) * COUT + o];
        }
        float y = g + h;
        s1 += y;
        s2 += y * y;
        gx = fmaxf(gx, g);
        gn = fminf(gn, g);
    }
    MaxY[base * COUT + o] = gx + h;
    MinY[base * COUT + o] = gn + h;

    __shared__ float ls[2 * COUT];
    if (threadIdx.y == 0) { ls[o] = 0.f; ls[COUT + o] = 0.f; }
    __syncthreads();
    atomicAdd(&ls[o], s1);
    atomicAdd(&ls[COUT + o], s2);
    __syncthreads();
    if (threadIdx.y == 0) {
        atomicAdd(&stats[o], ls[o]);
        atomicAdd(&stats[64 + o], ls[COUT + o]);
    }
}

// stats: [0:64) sum, [64:128) sumsq, [128:192) scale, [192:256) shift
__global__ void finalize_kernel(const float* __restrict__ g, const float* __restrict__ bb,
                                float* __restrict__ stats, int cout, float invP) {
    int o = threadIdx.x;
    if (o >= cout) return;
    float mu  = stats[o] * invP;
    float var = stats[64 + o] * invP - mu * mu;
    float sc  = g[o] * rsqrtf(var + EPSV);
    stats[128 + o] = sc;
    stats[192 + o] = bb[o] - mu * sc;
}

// out[b][o][n] = lrelu(scale*(scale>=0 ? MaxY : MinY) + shift); lrelu/affine monotone.
__global__ void apply_kernel(const float* __restrict__ MaxY, const float* __restrict__ MinY,
                             const float* __restrict__ stats, float* __restrict__ out, int cout) {
    int e = blockIdx.x * 256 + threadIdx.x;
    if (e >= BB * 64 * NN) return;
    int total = BB * cout * NN;
    if (e >= total) return;
    int n = e & (NN - 1);
    int o = (e >> 12) % cout;
    int b = e / (NN * cout);
    float sc = stats[128 + o], sh = stats[192 + o];
    int si = (b * NN + n) * cout + o;
    float v = (sc >= 0.f) ? MaxY[si] : MinY[si];
    out[e] = lrelu(sc * v + sh);
}

// h.reshape(1,-1,128).mean(axis=1): bin by (flat index mod 128)
__global__ void mean_kernel(const float* __restrict__ xd1, const float* __restrict__ xd2,
                            float* __restrict__ hsum) {
    __shared__ float bins[128];
    const int tid = threadIdx.x;
    if (tid < 128) bins[tid] = 0.f;
    __syncthreads();
    const int half = BB * 64 * NN;
    const int stride = gridDim.x * 256;
    for (int e = blockIdx.x * 256 + tid; e < half; e += stride)
        atomicAdd(&bins[e & 127], xd1[e]);
    for (int e = blockIdx.x * 256 + tid; e < half; e += stride)
        atomicAdd(&bins[e & 127], xd2[e]);
    __syncthreads();
    if (tid < 128) atomicAdd(&hsum[tid], bins[tid]);
}

__global__ void head_kernel(const float* __restrict__ hsum,
                            const float* __restrict__ W2d, const float* __restrict__ b2d,
                            const float* __restrict__ W3d, const float* __restrict__ b3d,
                            const float* __restrict__ W4d, const float* __restrict__ b4d,
                            float* __restrict__ out) {
    __shared__ float h[128], t1[128], t2[64];
    const int t = threadIdx.x;
    h[t] = hsum[t] * (1.f / 32768.f);
    __syncthreads();
    float a = b2d[t];
    for (int j = 0; j < 128; j++) a += W2d[t * 128 + j] * h[j];
    t1[t] = lrelu(a);
    __syncthreads();
    if (t < 64) {
        float a2 = b3d[t];
        for (int j = 0; j < 128; j++) a2 += W3d[t * 128 + j] * t1[j];
        t2[t] = lrelu(a2);
    }
    __syncthreads();
    if (t < 11) {
        float a3 = b4d[t];
        for (int j = 0; j < 64; j++) a3 += W4d[t * 64 + j] * t2[j];
        out[t] = lrelu(a3);
    }
}

extern "C" void kernel_launch(void* const* d_in, const int* in_sizes, int n_in,
                              void* d_out, int out_size, void* d_ws, size_t ws_size,
                              hipStream_t stream) {
    const float* x   = (const float*)d_in[0];
    const float* w1  = (const float*)d_in[1];
    const float* g1  = (const float*)d_in[2];
    const float* b1  = (const float*)d_in[3];
    const float* w2  = (const float*)d_in[4];
    const float* g2  = (const float*)d_in[5];
    const float* b2  = (const float*)d_in[6];
    const float* wd1 = (const float*)d_in[7];
    const float* gd1 = (const float*)d_in[8];
    const float* bd1 = (const float*)d_in[9];
    const float* wd2 = (const float*)d_in[10];
    const float* gd2 = (const float*)d_in[11];
    const float* bd2 = (const float*)d_in[12];
    const float* W2d = (const float*)d_in[13];
    const float* b2d = (const float*)d_in[14];
    const float* W3d = (const float*)d_in[15];
    const float* b3d = (const float*)d_in[16];
    const float* W4d = (const float*)d_in[17];
    const float* b4d = (const float*)d_in[18];
    float* out = (float*)d_out;

    char* ws = (char*)d_ws;
    size_t off = 0;
    auto alloc = [&](size_t bytes) { char* p = ws + off; off += (bytes + 255) & ~size_t(255); return p; };
    int*   idx1  = (int*)  alloc(BB * NN * KK * 4);
    int*   idx2  = (int*)  alloc(BB * NN * KK * 4);
    int*   idx3  = (int*)  alloc(BB * NN * KK * 4);
    float* x1m   = (float*)alloc(BB * 32 * NN * 4);
    float* x2m   = (float*)alloc(BB * 64 * NN * 4);
    float* xd1   = (float*)alloc(BB * 64 * NN * 4);
    float* xd2   = (float*)alloc(BB * 64 * NN * 4);
    float* G1    = (float*)alloc((size_t)BB * NN * 64 * 4);
    float* G2    = (float*)alloc((size_t)BB * NN * 64 * 4);
    float* H     = (float*)alloc((size_t)BB * NN * 64 * 4);
    float* MaxY  = (float*)alloc((size_t)BB * NN * 64 * 4);
    float* MinY  = (float*)alloc((size_t)BB * NN * 64 * 4);
    float* stats = (float*)alloc(256 * 4);
    float* hsum  = (float*)alloc(128 * 4);

    const float invP = 1.f / (float)(BB * NN * KK);
    const dim3 knn_grid(NN / 64, BB);

    zero_kernel<<<1, 256, 0, stream>>>(hsum, 128);

    // --- kNN on x (C=3) ---
    knn_kernel<3><<<knn_grid, 256, 0, stream>>>(x, idx1);

    // --- conv1: Cout=32, group (x, idx1, C=3), w1 CIN=6 ---
    zero_kernel<<<1, 256, 0, stream>>>(stats, 128);
    precompute_kernel<32><<<dim3(NN / 64, BB), dim3(32, 8), 2 * 3 * 32 * 4, stream>>>(
        x, 3, w1, 6, 0, 3, G1, H, 1, 1);
    conv_stats_kernel<32, 1><<<dim3(NN / 8, BB), dim3(32, 8), 0, stream>>>(
        G1, idx1, nullptr, nullptr, H, stats, MaxY, MinY);
    finalize_kernel<<<1, 64, 0, stream>>>(g1, b1, stats, 32, invP);
    apply_kernel<<<(BB * 32 * NN + 255) / 256, 256, 0, stream>>>(MaxY, MinY, stats, x1m, 32);

    // --- kNN on x1_max (C=32) ---
    knn_kernel<32><<<knn_grid, 256, 0, stream>>>(x1m, idx2);

    // --- conv2: Cout=64, groups (x, idx1, 3) + (x1m, idx2, 32), w2 CIN=70 ---
    zero_kernel<<<1, 256, 0, stream>>>(stats, 128);
    precompute_kernel<64><<<dim3(NN / 64, BB), dim3(64, 4), 2 * 3 * 64 * 4, stream>>>(
        x, 3, w2, 70, 0, 3, G1, H, 1, 1);
    precompute_kernel<64><<<dim3(NN / 64, BB), dim3(64, 4), 2 * 32 * 64 * 4, stream>>>(
        x1m, 32, w2, 70, 6, 38, G2, H, 1, 0);
    conv_stats_kernel<64, 2><<<dim3(NN / 4, BB), dim3(64, 4), 0, stream>>>(
        G1, idx1, G2, idx2, H, stats, MaxY, MinY);
    finalize_kernel<<<1, 64, 0, stream>>>(g2, b2, stats, 64, invP);
    apply_kernel<<<(BB * 64 * NN + 255) / 256, 256, 0, stream>>>(MaxY, MinY, stats, x2m, 64);

    // --- convd1: Cout=64, group (x1m, idx2, 32), wd1 CIN=64 ---
    zero_kernel<<<1, 256, 0, stream>>>(stats, 128);
    precompute_kernel<64><<<dim3(NN / 64, BB), dim3(64, 4), 2 * 32 * 64 * 4, stream>>>(
        x1m, 32, wd1, 64, 0, 32, G1, H, 1, 1);
    conv_stats_kernel<64, 1><<<dim3(NN / 4, BB), dim3(64, 4), 0, stream>>>(
        G1, idx2, nullptr, nullptr, H, stats, MaxY, MinY);
    finalize_kernel<<<1, 64, 0, stream>>>(gd1, bd1, stats, 64, invP);
    apply_kernel<<<(BB * 64 * NN + 255) / 256, 256, 0, stream>>>(MaxY, MinY, stats, xd1, 64);

    // --- kNN on x2_max (C=64) ---
    knn_kernel<64><<<knn_grid, 256, 0, stream>>>(x2m, idx3);

    // --- convd2: Cout=64, group (x2m, idx3, 64), wd2 CIN=128 ---
    zero_kernel<<<1, 256, 0, stream>>>(stats, 128);
    precompute_kernel<64><<<dim3(NN / 64, BB), dim3(64, 4), 2 * 64 * 64 * 4, stream>>>(
        x2m, 64, wd2, 128, 0, 64, G1, H, 1, 1);
    conv_stats_kernel<64, 1><<<dim3(NN / 4, BB), dim3(64, 4), 0, stream>>>(
        G1, idx3, nullptr, nullptr, H, stats, MaxY, MinY);
    finalize_kernel<<<1, 64, 0, stream>>>(gd2, bd2, stats, 64, invP);
    apply_kernel<<<(BB * 64 * NN + 255) / 256, 256, 0, stream>>>(MaxY, MinY, stats, xd2, 64);

    // --- global mean + MLP head ---
    mean_kernel<<<1024, 256, 0, stream>>>(xd1, xd2, hsum);
    head_kernel<<<1, 128, 0, stream>>>(hsum, W2d, b2d, W3d, b3d, W4d, b4d, out);
}

// Round 2
// 2013.888 us; speedup vs baseline: 3.2906x; 3.2906x over previous
//
#include <hip/hip_runtime.h>

#define BB 8
#define NN 4096
#define KK 20
constexpr float EPSV = 1e-5f;
constexpr float SLOPE = 0.2f;

__device__ __forceinline__ float lrelu(float v) { return v >= 0.f ? v : SLOPE * v; }

__global__ void zero_kernel(float* p, int n) {
    int i = blockIdx.x * 256 + threadIdx.x;
    if (i < n) p[i] = 0.f;
}

// 0.5*||x_n||^2 per point. grid (NN/256, BB), block 256.
template<int C>
__global__ void halfnorm_kernel(const float* __restrict__ src, float* __restrict__ hng) {
    int n = blockIdx.x * 256 + threadIdx.x;
    int b = blockIdx.y;
    float s = 0.f;
    #pragma unroll
    for (int c = 0; c < C; c++) { float v = src[(b * C + c) * NN + n]; s += v * v; }
    hng[b * NN + n] = 0.5f * s;
}

// ---------------- kNN: fused distance tiles + threshold-filtered top-20 ----------------
// grid (N/64, B), block 256. Score s(q,m) = dot(q,m) - 0.5*||x_m||^2 (same top-k set
// as reference d). Compute threads filter scores against per-query threshold tau
// (20th-best so far) and append rare passers to an LDS pool; wave 0 drains pools into
// register-resident sorted top-20 lists once per chunk (unrolled bubble insertion).
template<int C>
__global__ __launch_bounds__(256) void knn_kernel(const float* __restrict__ src,
                                                  const float* __restrict__ hng,
                                                  int* __restrict__ idx) {
    __shared__ __align__(16) float qf[C * 64];     // [c][q]
    __shared__ __align__(16) float cf[C * 64];     // [c][m]
    __shared__ __align__(16) float hn[64];
    __shared__ float pv[64 * 65];                  // pool values, padded stride
    __shared__ unsigned short pidx[64 * 66];       // pool candidate ids, padded stride
    __shared__ float tau[64];
    __shared__ int   cnt[64];

    const int b = blockIdx.y;
    const int q0 = blockIdx.x * 64;
    const int tid = threadIdx.x;

    // load query fragments (float4, coalesced)
    for (int i = tid; i < C * 16; i += 256) {
        int c = i >> 4, j = (i & 15) * 4;
        *(float4*)(qf + c * 64 + j) = *(const float4*)(src + (b * C + c) * NN + q0 + j);
    }
    if (tid < 64) { tau[tid] = -3.4e38f; cnt[tid] = 0; }

    // wave-0 register top-20 (ascending: tv[0]=threshold, tv[19]=best)
    float tv[20]; int ti[20];
    #pragma unroll
    for (int k = 0; k < 20; k++) { tv[k] = -3.4e38f; ti[k] = 0; }
    __syncthreads();

    const int qi = (tid & 15) * 4;
    const int mi = (tid >> 4) * 4;

    for (int ch = 0; ch < 64; ch++) {
        const int m0 = ch * 64;
        // stage candidate fragments + half-norms
        for (int i = tid; i < C * 16; i += 256) {
            int c = i >> 4, j = (i & 15) * 4;
            *(float4*)(cf + c * 64 + j) = *(const float4*)(src + (b * C + c) * NN + m0 + j);
        }
        if (tid < 16) *(float4*)(hn + tid * 4) = *(const float4*)(hng + b * NN + m0 + tid * 4);
        __syncthreads();

        // 4x4 register-tile dot products
        float acc[4][4] = {};
        #pragma unroll 4
        for (int c = 0; c < C; c++) {
            const float4 qv = *(const float4*)(qf + c * 64 + qi);
            const float4 mv = *(const float4*)(cf + c * 64 + mi);
            float qa[4] = {qv.x, qv.y, qv.z, qv.w};
            float ma[4] = {mv.x, mv.y, mv.z, mv.w};
            #pragma unroll
            for (int i2 = 0; i2 < 4; i2++)
                #pragma unroll
                for (int j2 = 0; j2 < 4; j2++)
                    acc[i2][j2] += qa[i2] * ma[j2];
        }

        float t4[4], h4[4];
        #pragma unroll
        for (int i2 = 0; i2 < 4; i2++) t4[i2] = tau[qi + i2];
        #pragma unroll
        for (int j2 = 0; j2 < 4; j2++) h4[j2] = hn[mi + j2];

        // threshold filter + pool append (rare after warm-up)
        #pragma unroll
        for (int i2 = 0; i2 < 4; i2++) {
            #pragma unroll
            for (int j2 = 0; j2 < 4; j2++) {
                float s = acc[i2][j2] - h4[j2];
                if (s > t4[i2]) {
                    int q = qi + i2;
                    int p = atomicAdd(&cnt[q], 1);   // bounded by 64/chunk: fits
                    pv[q * 65 + p] = s;
                    pidx[q * 66 + p] = (unsigned short)(m0 + mi + j2);
                }
            }
        }
        __syncthreads();

        // wave 0: drain pool into register top-20, republish tau
        if (tid < 64) {
            int n = cnt[tid];
            for (int t = 0; t < n; t++) {
                float v = pv[tid * 65 + t];
                if (v > tv[0]) {
                    tv[0] = v; ti[0] = (int)pidx[tid * 66 + t];
                    #pragma unroll
                    for (int j = 0; j < 19; j++) {
                        if (tv[j] > tv[j + 1]) {
                            float a = tv[j]; tv[j] = tv[j + 1]; tv[j + 1] = a;
                            int bi = ti[j]; ti[j] = ti[j + 1]; ti[j + 1] = bi;
                        }
                    }
                }
            }
            cnt[tid] = 0;
            tau[tid] = tv[0];
        }
        __syncthreads();
    }

    if (tid < 64) {
        #pragma unroll
        for (int k = 0; k < 20; k++)
            idx[(b * NN + q0 + tid) * KK + k] = ti[k];   // order irrelevant downstream
    }
}

// ---------------- conv precompute: G = Wd*src, H = (Wc-Wd)*src ----------------
template<int COUT>
__global__ void precompute_kernel(const float* __restrict__ src, int C,
                                  const float* __restrict__ w, int CIN, int wd_off, int wc_off,
                                  float* __restrict__ G, float* __restrict__ H,
                                  int initG, int initH) {
    constexpr int MY = 256 / COUT;
    extern __shared__ float lds[];
    float* wd = lds;
    float* wc = lds + C * COUT;
    const int b = blockIdx.y;
    const int tid = threadIdx.y * COUT + threadIdx.x;
    for (int i = tid; i < C * COUT; i += 256) {
        int c = i / COUT, o = i % COUT;
        float a  = w[o * CIN + wd_off + c];
        float cc = w[o * CIN + wc_off + c];
        wd[i] = a;
        wc[i] = cc - a;
    }
    __syncthreads();
    const int o = threadIdx.x;
    for (int it = 0; it < COUT / 4; it++) {
        int m = blockIdx.x * 64 + it * MY + threadIdx.y;
        float g = 0.f, h = 0.f;
        for (int c = 0; c < C; c++) {
            float s = src[(b * C + c) * NN + m];
            g += wd[c * COUT + o] * s;
            h += wc[c * COUT + o] * s;
        }
        int gi = (b * NN + m) * COUT + o;
        if (initG) G[gi] = g; else G[gi] += g;
        if (initH) H[gi] = h; else H[gi] += h;
    }
}

// ---------------- conv stats + per-(b,n,o) min/max over k ----------------
template<int COUT, int GROUPS>
__global__ void conv_stats_kernel(const float* __restrict__ G1, const int* __restrict__ idx1,
                                  const float* __restrict__ G2, const int* __restrict__ idx2,
                                  const float* __restrict__ H, float* __restrict__ stats,
                                  float* __restrict__ MaxY, float* __restrict__ MinY) {
    constexpr int NY = 256 / COUT;
    const int b = blockIdx.y;
    const int o = threadIdx.x;
    const int n = blockIdx.x * NY + threadIdx.y;
    const int base = b * NN + n;
    const float h = H[base * COUT + o];
    float s1 = 0.f, s2 = 0.f;
    float gx = -3.4e38f, gn = 3.4e38f;
    #pragma unroll
    for (int k = 0; k < KK; k++) {
        int i1 = idx1[base * KK + k];
        float g = G1[(b * NN + i1) * COUT + o];
        if (GROUPS == 2) {
            int i2 = idx2[base * KK + k];
            g += G2[(b * NN + i2) * COUT + o];
        }
        float y = g + h;
        s1 += y;
        s2 += y * y;
        gx = fmaxf(gx, g);
        gn = fminf(gn, g);
    }
    MaxY[base * COUT + o] = gx + h;
    MinY[base * COUT + o] = gn + h;

    __shared__ float ls[2 * COUT];
    if (threadIdx.y == 0) { ls[o] = 0.f; ls[COUT + o] = 0.f; }
    __syncthreads();
    atomicAdd(&ls[o], s1);
    atomicAdd(&ls[COUT + o], s2);
    __syncthreads();
    if (threadIdx.y == 0) {
        atomicAdd(&stats[o], ls[o]);
        atomicAdd(&stats[64 + o], ls[COUT + o]);
    }
}

__global__ void finalize_kernel(const float* __restrict__ g, const float* __restrict__ bb,
                                float* __restrict__ stats, int cout, float invP) {
    int o = threadIdx.x;
    if (o >= cout) return;
    float mu  = stats[o] * invP;
    float var = stats[64 + o] * invP - mu * mu;
    float sc  = g[o] * rsqrtf(var + EPSV);
    stats[128 + o] = sc;
    stats[192 + o] = bb[o] - mu * sc;
}

__global__ void apply_kernel(const float* __restrict__ MaxY, const float* __restrict__ MinY,
                             const float* __restrict__ stats, float* __restrict__ out, int cout) {
    int e = blockIdx.x * 256 + threadIdx.x;
    int total = BB * cout * NN;
    if (e >= total) return;
    int n = e & (NN - 1);
    int o = (e >> 12) % cout;
    int b = e / (NN * cout);
    float sc = stats[128 + o], sh = stats[192 + o];
    int si = (b * NN + n) * cout + o;
    float v = (sc >= 0.f) ? MaxY[si] : MinY[si];
    out[e] = lrelu(sc * v + sh);
}

__global__ void mean_kernel(const float* __restrict__ xd1, const float* __restrict__ xd2,
                            float* __restrict__ hsum) {
    __shared__ float bins[128];
    const int tid = threadIdx.x;
    if (tid < 128) bins[tid] = 0.f;
    __syncthreads();
    const int half = BB * 64 * NN;
    const int stride = gridDim.x * 256;
    for (int e = blockIdx.x * 256 + tid; e < half; e += stride)
        atomicAdd(&bins[e & 127], xd1[e]);
    for (int e = blockIdx.x * 256 + tid; e < half; e += stride)
        atomicAdd(&bins[e & 127], xd2[e]);
    __syncthreads();
    if (tid < 128) atomicAdd(&hsum[tid], bins[tid]);
}

__global__ void head_kernel(const float* __restrict__ hsum,
                            const float* __restrict__ W2d, const float* __restrict__ b2d,
                            const float* __restrict__ W3d, const float* __restrict__ b3d,
                            const float* __restrict__ W4d, const float* __restrict__ b4d,
                            float* __restrict__ out) {
    __shared__ float h[128], t1[128], t2[64];
    const int t = threadIdx.x;
    h[t] = hsum[t] * (1.f / 32768.f);
    __syncthreads();
    float a = b2d[t];
    for (int j = 0; j < 128; j++) a += W2d[t * 128 + j] * h[j];
    t1[t] = lrelu(a);
    __syncthreads();
    if (t < 64) {
        float a2 = b3d[t];
        for (int j = 0; j < 128; j++) a2 += W3d[t * 128 + j] * t1[j];
        t2[t] = lrelu(a2);
    }
    __syncthreads();
    if (t < 11) {
        float a3 = b4d[t];
        for (int j = 0; j < 64; j++) a3 += W4d[t * 64 + j] * t2[j];
        out[t] = lrelu(a3);
    }
}

extern "C" void kernel_launch(void* const* d_in, const int* in_sizes, int n_in,
                              void* d_out, int out_size, void* d_ws, size_t ws_size,
                              hipStream_t stream) {
    const float* x   = (const float*)d_in[0];
    const float* w1  = (const float*)d_in[1];
    const float* g1  = (const float*)d_in[2];
    const float* b1  = (const float*)d_in[3];
    const float* w2  = (const float*)d_in[4];
    const float* g2  = (const float*)d_in[5];
    const float* b2  = (const float*)d_in[6];
    const float* wd1 = (const float*)d_in[7];
    const float* gd1 = (const float*)d_in[8];
    const float* bd1 = (const float*)d_in[9];
    const float* wd2 = (const float*)d_in[10];
    const float* gd2 = (const float*)d_in[11];
    const float* bd2 = (const float*)d_in[12];
    const float* W2d = (const float*)d_in[13];
    const float* b2d = (const float*)d_in[14];
    const float* W3d = (const float*)d_in[15];
    const float* b3d = (const float*)d_in[16];
    const float* W4d = (const float*)d_in[17];
    const float* b4d = (const float*)d_in[18];
    float* out = (float*)d_out;

    char* ws = (char*)d_ws;
    size_t off = 0;
    auto alloc = [&](size_t bytes) { char* p = ws + off; off += (bytes + 255) & ~size_t(255); return p; };
    int*   idx1  = (int*)  alloc(BB * NN * KK * 4);
    int*   idx2  = (int*)  alloc(BB * NN * KK * 4);
    int*   idx3  = (int*)  alloc(BB * NN * KK * 4);
    float* x1m   = (float*)alloc(BB * 32 * NN * 4);
    float* x2m   = (float*)alloc(BB * 64 * NN * 4);
    float* xd1   = (float*)alloc(BB * 64 * NN * 4);
    float* xd2   = (float*)alloc(BB * 64 * NN * 4);
    float* G1    = (float*)alloc((size_t)BB * NN * 64 * 4);
    float* G2    = (float*)alloc((size_t)BB * NN * 64 * 4);
    float* H     = (float*)alloc((size_t)BB * NN * 64 * 4);
    float* MaxY  = (float*)alloc((size_t)BB * NN * 64 * 4);
    float* MinY  = (float*)alloc((size_t)BB * NN * 64 * 4);
    float* stats = (float*)alloc(256 * 4);
    float* hsum  = (float*)alloc(128 * 4);
    float* hng   = (float*)alloc(BB * NN * 4);

    const float invP = 1.f / (float)(BB * NN * KK);
    const dim3 knn_grid(NN / 64, BB);
    const dim3 hn_grid(NN / 256, BB);

    zero_kernel<<<1, 256, 0, stream>>>(hsum, 128);

    // --- kNN on x (C=3) ---
    halfnorm_kernel<3><<<hn_grid, 256, 0, stream>>>(x, hng);
    knn_kernel<3><<<knn_grid, 256, 0, stream>>>(x, hng, idx1);

    // --- conv1: Cout=32, group (x, idx1, C=3), w1 CIN=6 ---
    zero_kernel<<<1, 256, 0, stream>>>(stats, 128);
    precompute_kernel<32><<<dim3(NN / 64, BB), dim3(32, 8), 2 * 3 * 32 * 4, stream>>>(
        x, 3, w1, 6, 0, 3, G1, H, 1, 1);
    conv_stats_kernel<32, 1><<<dim3(NN / 8, BB), dim3(32, 8), 0, stream>>>(
        G1, idx1, nullptr, nullptr, H, stats, MaxY, MinY);
    finalize_kernel<<<1, 64, 0, stream>>>(g1, b1, stats, 32, invP);
    apply_kernel<<<(BB * 32 * NN + 255) / 256, 256, 0, stream>>>(MaxY, MinY, stats, x1m, 32);

    // --- kNN on x1_max (C=32) ---
    halfnorm_kernel<32><<<hn_grid, 256, 0, stream>>>(x1m, hng);
    knn_kernel<32><<<knn_grid, 256, 0, stream>>>(x1m, hng, idx2);

    // --- conv2: Cout=64, groups (x, idx1, 3) + (x1m, idx2, 32), w2 CIN=70 ---
    zero_kernel<<<1, 256, 0, stream>>>(stats, 128);
    precompute_kernel<64><<<dim3(NN / 64, BB), dim3(64, 4), 2 * 3 * 64 * 4, stream>>>(
        x, 3, w2, 70, 0, 3, G1, H, 1, 1);
    precompute_kernel<64><<<dim3(NN / 64, BB), dim3(64, 4), 2 * 32 * 64 * 4, stream>>>(
        x1m, 32, w2, 70, 6, 38, G2, H, 1, 0);
    conv_stats_kernel<64, 2><<<dim3(NN / 4, BB), dim3(64, 4), 0, stream>>>(
        G1, idx1, G2, idx2, H, stats, MaxY, MinY);
    finalize_kernel<<<1, 64, 0, stream>>>(g2, b2, stats, 64, invP);
    apply_kernel<<<(BB * 64 * NN + 255) / 256, 256, 0, stream>>>(MaxY, MinY, stats, x2m, 64);

    // --- convd1: Cout=64, group (x1m, idx2, 32), wd1 CIN=64 ---
    zero_kernel<<<1, 256, 0, stream>>>(stats, 128);
    precompute_kernel<64><<<dim3(NN / 64, BB), dim3(64, 4), 2 * 32 * 64 * 4, stream>>>(
        x1m, 32, wd1, 64, 0, 32, G1, H, 1, 1);
    conv_stats_kernel<64, 1><<<dim3(NN / 4, BB), dim3(64, 4), 0, stream>>>(
        G1, idx2, nullptr, nullptr, H, stats, MaxY, MinY);
    finalize_kernel<<<1, 64, 0, stream>>>(gd1, bd1, stats, 64, invP);
    apply_kernel<<<(BB * 64 * NN + 255) / 256, 256, 0, stream>>>(MaxY, MinY, stats, xd1, 64);

    // --- kNN on x2_max (C=64) ---
    halfnorm_kernel<64><<<hn_grid, 256, 0, stream>>>(x2m, hng);
    knn_kernel<64><<<knn_grid, 256, 0, stream>>>(x2m, hng, idx3);

    // --- convd2: Cout=64, group (x2m, idx3, 64), wd2 CIN=128 ---
    zero_kernel<<<1, 256, 0, stream>>>(stats, 128);
    precompute_kernel<64><<<dim3(NN / 64, BB), dim3(64, 4), 2 * 64 * 64 * 4, stream>>>(
        x2m, 64, wd2, 128, 0, 64, G1, H, 1, 1);
    conv_stats_kernel<64, 1><<<dim3(NN / 4, BB), dim3(64, 4), 0, stream>>>(
        G1, idx3, nullptr, nullptr, H, stats, MaxY, MinY);
    finalize_kernel<<<1, 64, 0, stream>>>(gd2, bd2, stats, 64, invP);
    apply_kernel<<<(BB * 64 * NN + 255) / 256, 256, 0, stream>>>(MaxY, MinY, stats, xd2, 64);

    // --- global mean + MLP head ---
    mean_kernel<<<1024, 256, 0, stream>>>(xd1, xd2, hsum);
    head_kernel<<<1, 128, 0, stream>>>(hsum, W2d, b2d, W3d, b3d, W4d, b4d, out);
}

// Round 3
// 1760.073 us; speedup vs baseline: 3.7652x; 1.1442x over previous
//
#include <hip/hip_runtime.h>

#define BB 8
#define NN 4096
#define KK 20
constexpr float EPSV = 1e-5f;
constexpr float SLOPE = 0.2f;

typedef __bf16 bfrag __attribute__((ext_vector_type(8)));
typedef float floatx4 __attribute__((ext_vector_type(4)));
typedef unsigned short us4 __attribute__((ext_vector_type(4)));

__device__ __forceinline__ float lrelu(float v) { return v >= 0.f ? v : SLOPE * v; }

__device__ __forceinline__ unsigned short bf16rn(float f) {
    unsigned int u = __float_as_uint(f);
    return (unsigned short)((u + 0x7FFFu + ((u >> 16) & 1u)) >> 16);
}
__device__ __forceinline__ float bf16up(unsigned short h) {
    return __uint_as_float(((unsigned int)h) << 16);
}

__global__ void zero_kernel(float* p, int n) {
    int i = blockIdx.x * 256 + threadIdx.x;
    if (i < n) p[i] = 0.f;
}

// 0.5*||x_n||^2 per point (exact fp32). grid (NN/256, BB), block 256.
template<int C>
__global__ void halfnorm_kernel(const float* __restrict__ src, float* __restrict__ hng) {
    int n = blockIdx.x * 256 + threadIdx.x;
    int b = blockIdx.y;
    float s = 0.f;
    #pragma unroll
    for (int c = 0; c < C; c++) { float v = src[(b * C + c) * NN + n]; s += v * v; }
    hng[b * NN + n] = 0.5f * s;
}

// ---------------- kNN via MFMA (bf16 hi/lo split, 4-term exact) ----------------
// Score s(q,m) = dot(q,m) - 0.5||x_m||^2 (same top-k set as reference).
// dot = qh*ch + qh*cl + ql*ch + ql*cl with x = hi + lo; bf16 products exact in fp32.
// Block 256 (4 waves); tile 64q x 64m per chunk; wave owns 32x32 (4 MFMA acc tiles).
// Threshold filter + LDS pool + wave-0 drain (register top-20) as before.
template<int C>
__global__ __launch_bounds__(256) void knn_kernel(const float* __restrict__ src,
                                                  const float* __restrict__ hng,
                                                  int* __restrict__ idx) {
    constexpr int SK = (C == 3) ? 40 : (2 * C + 8);   // padded k-stride (shorts)
    __shared__ unsigned short qpack[64 * SK];
    __shared__ unsigned short cpack[64 * SK];
    __shared__ float hn[64];
    __shared__ float pv[64 * 65];
    __shared__ unsigned short pidx[64 * 66];
    __shared__ float tau[64];
    __shared__ int   cnt[64];

    const int b = blockIdx.y;
    const int q0 = blockIdx.x * 64;
    const int tid = threadIdx.x;
    const int lane = tid & 63;
    const int wv = tid >> 6;
    const int wr = (wv >> 1) * 32;      // wave q-offset in [0,64)
    const int wc = (wv & 1) * 32;       // wave m-offset in [0,64)
    const int fl = lane & 15;
    const int fq = lane >> 4;

    // ---- stage queries (hi/lo bf16) ----
    if (C == 3) {
        // zero pad region k in [12,32) for both qpack and cpack rows
        for (int i = tid; i < 64 * 20; i += 256) {
            int r = i / 20, k = 12 + i % 20;
            qpack[r * SK + k] = 0; cpack[r * SK + k] = 0;
        }
        if (tid < 64) {
            int q = tid;
            #pragma unroll
            for (int c = 0; c < 3; c++) {
                float v = src[(b * 3 + c) * NN + q0 + q];
                unsigned short h = bf16rn(v);
                unsigned short l = bf16rn(v - bf16up(h));
                // A-pack: [qh(3) | ql(3) | qh(3) | ql(3) | 0...]
                qpack[q * SK + c] = h;  qpack[q * SK + 3 + c] = l;
                qpack[q * SK + 6 + c] = h;  qpack[q * SK + 9 + c] = l;
            }
        }
    } else {
        for (int t = 0; t < C / 16; t++) {
            int i = t * 256 + tid;
            int c4 = (i >> 6) * 4, m = i & 63;
            us4 hv, lv;
            #pragma unroll
            for (int j = 0; j < 4; j++) {
                float v = src[(b * C + c4 + j) * NN + q0 + m];
                unsigned short h = bf16rn(v);
                hv[j] = h;
                lv[j] = bf16rn(v - bf16up(h));
            }
            *(us4*)(&qpack[m * SK + c4]) = hv;          // qh region [0,C)
            *(us4*)(&qpack[m * SK + C + c4]) = lv;      // ql region [C,2C)
        }
    }
    if (tid < 64) { tau[tid] = -3.4e38f; cnt[tid] = 0; }

    float tv[20]; int ti[20];
    #pragma unroll
    for (int k = 0; k < 20; k++) { tv[k] = -3.4e38f; ti[k] = 0; }
    __syncthreads();

    for (int ch = 0; ch < 64; ch++) {
        const int m0 = ch * 64;
        // ---- stage candidates ----
        if (C == 3) {
            if (tid < 64) {
                int m = tid;
                #pragma unroll
                for (int c = 0; c < 3; c++) {
                    float v = src[(b * 3 + c) * NN + m0 + m];
                    unsigned short h = bf16rn(v);
                    unsigned short l = bf16rn(v - bf16up(h));
                    // B-pack: [ch(3) | cl(3) | cl(3) | ch(3) | 0...] -> hh+ll+hl+lh
                    cpack[m * SK + c] = h;  cpack[m * SK + 3 + c] = l;
                    cpack[m * SK + 6 + c] = l;  cpack[m * SK + 9 + c] = h;
                }
            }
        } else {
            for (int t = 0; t < C / 16; t++) {
                int i = t * 256 + tid;
                int c4 = (i >> 6) * 4, m = i & 63;
                us4 hv, lv;
                #pragma unroll
                for (int j = 0; j < 4; j++) {
                    float v = src[(b * C + c4 + j) * NN + m0 + m];
                    unsigned short h = bf16rn(v);
                    hv[j] = h;
                    lv[j] = bf16rn(v - bf16up(h));
                }
                *(us4*)(&cpack[m * SK + c4]) = hv;
                *(us4*)(&cpack[m * SK + C + c4]) = lv;
            }
        }
        if (tid < 16) *(float4*)(hn + tid * 4) = *(const float4*)(hng + b * NN + m0 + tid * 4);
        __syncthreads();

        // ---- MFMA: acc[r2][c2] = 32x32 wave tile scores ----
        floatx4 acc[2][2];
        #pragma unroll
        for (int r2 = 0; r2 < 2; r2++)
            #pragma unroll
            for (int c2 = 0; c2 < 2; c2++)
                acc[r2][c2] = (floatx4)(0.f);

        if (C == 3) {
            #pragma unroll
            for (int r2 = 0; r2 < 2; r2++) {
                bfrag a = *(const bfrag*)(&qpack[(wr + r2 * 16 + fl) * SK + fq * 8]);
                #pragma unroll
                for (int c2 = 0; c2 < 2; c2++) {
                    bfrag bm = *(const bfrag*)(&cpack[(wc + c2 * 16 + fl) * SK + fq * 8]);
                    acc[r2][c2] = __builtin_amdgcn_mfma_f32_16x16x32_bf16(a, bm, acc[r2][c2], 0, 0, 0);
                }
            }
        } else {
            #pragma unroll
            for (int kk = 0; kk < C / 32; kk++) {
                const int kb = kk * 32 + fq * 8;
                bfrag ah[2], al[2], bh[2], bl[2];
                #pragma unroll
                for (int r2 = 0; r2 < 2; r2++) {
                    ah[r2] = *(const bfrag*)(&qpack[(wr + r2 * 16 + fl) * SK + kb]);
                    al[r2] = *(const bfrag*)(&qpack[(wr + r2 * 16 + fl) * SK + C + kb]);
                }
                #pragma unroll
                for (int c2 = 0; c2 < 2; c2++) {
                    bh[c2] = *(const bfrag*)(&cpack[(wc + c2 * 16 + fl) * SK + kb]);
                    bl[c2] = *(const bfrag*)(&cpack[(wc + c2 * 16 + fl) * SK + C + kb]);
                }
                #pragma unroll
                for (int r2 = 0; r2 < 2; r2++)
                    #pragma unroll
                    for (int c2 = 0; c2 < 2; c2++) {
                        acc[r2][c2] = __builtin_amdgcn_mfma_f32_16x16x32_bf16(ah[r2], bh[c2], acc[r2][c2], 0, 0, 0);
                        acc[r2][c2] = __builtin_amdgcn_mfma_f32_16x16x32_bf16(ah[r2], bl[c2], acc[r2][c2], 0, 0, 0);
                        acc[r2][c2] = __builtin_amdgcn_mfma_f32_16x16x32_bf16(al[r2], bh[c2], acc[r2][c2], 0, 0, 0);
                        acc[r2][c2] = __builtin_amdgcn_mfma_f32_16x16x32_bf16(al[r2], bl[c2], acc[r2][c2], 0, 0, 0);
                    }
            }
        }

        // ---- filter: C-layout col=lane&15, row=fq*4+reg ----
        float hnv[2];
        #pragma unroll
        for (int c2 = 0; c2 < 2; c2++) hnv[c2] = hn[wc + c2 * 16 + fl];
        #pragma unroll
        for (int r2 = 0; r2 < 2; r2++) {
            float4 t4 = *(const float4*)(&tau[wr + r2 * 16 + fq * 4]);
            float ta[4] = {t4.x, t4.y, t4.z, t4.w};
            #pragma unroll
            for (int c2 = 0; c2 < 2; c2++) {
                #pragma unroll
                for (int reg = 0; reg < 4; reg++) {
                    float s = acc[r2][c2][reg] - hnv[c2];
                    if (s > ta[reg]) {
                        int q = wr + r2 * 16 + fq * 4 + reg;
                        int p = atomicAdd(&cnt[q], 1);     // <= 64 per chunk: fits
                        pv[q * 65 + p] = s;
                        pidx[q * 66 + p] = (unsigned short)(m0 + wc + c2 * 16 + fl);
                    }
                }
            }
        }
        __syncthreads();

        // ---- wave-0 drain into register top-20 ----
        if (tid < 64) {
            int n = cnt[tid];
            for (int t = 0; t < n; t++) {
                float v = pv[tid * 65 + t];
                if (v > tv[0]) {
                    tv[0] = v; ti[0] = (int)pidx[tid * 66 + t];
                    #pragma unroll
                    for (int j = 0; j < 19; j++) {
                        if (tv[j] > tv[j + 1]) {
                            float a = tv[j]; tv[j] = tv[j + 1]; tv[j + 1] = a;
                            int bi = ti[j]; ti[j] = ti[j + 1]; ti[j + 1] = bi;
                        }
                    }
                }
            }
            cnt[tid] = 0;
            tau[tid] = tv[0];
        }
        __syncthreads();
    }

    if (tid < 64) {
        #pragma unroll
        for (int k = 0; k < 20; k++)
            idx[(b * NN + q0 + tid) * KK + k] = ti[k];   // order irrelevant downstream
    }
}

// ---------------- conv precompute: G = Wd*src, H = (Wc-Wd)*src ----------------
template<int COUT>
__global__ void precompute_kernel(const float* __restrict__ src, int C,
                                  const float* __restrict__ w, int CIN, int wd_off, int wc_off,
                                  float* __restrict__ G, float* __restrict__ H,
                                  int initG, int initH) {
    constexpr int MY = 256 / COUT;
    extern __shared__ float lds[];
    float* wd = lds;
    float* wc = lds + C * COUT;
    const int b = blockIdx.y;
    const int tid = threadIdx.y * COUT + threadIdx.x;
    for (int i = tid; i < C * COUT; i += 256) {
        int c = i / COUT, o = i % COUT;
        float a  = w[o * CIN + wd_off + c];
        float cc = w[o * CIN + wc_off + c];
        wd[i] = a;
        wc[i] = cc - a;
    }
    __syncthreads();
    const int o = threadIdx.x;
    for (int it = 0; it < COUT / 4; it++) {
        int m = blockIdx.x * 64 + it * MY + threadIdx.y;
        float g = 0.f, h = 0.f;
        for (int c = 0; c < C; c++) {
            float s = src[(b * C + c) * NN + m];
            g += wd[c * COUT + o] * s;
            h += wc[c * COUT + o] * s;
        }
        int gi = (b * NN + m) * COUT + o;
        if (initG) G[gi] = g; else G[gi] += g;
        if (initH) H[gi] = h; else H[gi] += h;
    }
}

// ---------------- conv stats + per-(b,n,o) min/max over k ----------------
template<int COUT, int GROUPS>
__global__ void conv_stats_kernel(const float* __restrict__ G1, const int* __restrict__ idx1,
                                  const float* __restrict__ G2, const int* __restrict__ idx2,
                                  const float* __restrict__ H, float* __restrict__ stats,
                                  float* __restrict__ MaxY, float* __restrict__ MinY) {
    constexpr int NY = 256 / COUT;
    const int b = blockIdx.y;
    const int o = threadIdx.x;
    const int n = blockIdx.x * NY + threadIdx.y;
    const int base = b * NN + n;
    const float h = H[base * COUT + o];
    float s1 = 0.f, s2 = 0.f;
    float gx = -3.4e38f, gn = 3.4e38f;
    #pragma unroll
    for (int k = 0; k < KK; k++) {
        int i1 = idx1[base * KK + k];
        float g = G1[(b * NN + i1) * COUT + o];
        if (GROUPS == 2) {
            int i2 = idx2[base * KK + k];
            g += G2[(b * NN + i2) * COUT + o];
        }
        float y = g + h;
        s1 += y;
        s2 += y * y;
        gx = fmaxf(gx, g);
        gn = fminf(gn, g);
    }
    MaxY[base * COUT + o] = gx + h;
    MinY[base * COUT + o] = gn + h;

    __shared__ float ls[2 * COUT];
    if (threadIdx.y == 0) { ls[o] = 0.f; ls[COUT + o] = 0.f; }
    __syncthreads();
    atomicAdd(&ls[o], s1);
    atomicAdd(&ls[COUT + o], s2);
    __syncthreads();
    if (threadIdx.y == 0) {
        atomicAdd(&stats[o], ls[o]);
        atomicAdd(&stats[64 + o], ls[COUT + o]);
    }
}

__global__ void finalize_kernel(const float* __restrict__ g, const float* __restrict__ bb,
                                float* __restrict__ stats, int cout, float invP) {
    int o = threadIdx.x;
    if (o >= cout) return;
    float mu  = stats[o] * invP;
    float var = stats[64 + o] * invP - mu * mu;
    float sc  = g[o] * rsqrtf(var + EPSV);
    stats[128 + o] = sc;
    stats[192 + o] = bb[o] - mu * sc;
}

__global__ void apply_kernel(const float* __restrict__ MaxY, const float* __restrict__ MinY,
                             const float* __restrict__ stats, float* __restrict__ out, int cout) {
    int e = blockIdx.x * 256 + threadIdx.x;
    int total = BB * cout * NN;
    if (e >= total) return;
    int n = e & (NN - 1);
    int o = (e >> 12) % cout;
    int b = e / (NN * cout);
    float sc = stats[128 + o], sh = stats[192 + o];
    int si = (b * NN + n) * cout + o;
    float v = (sc >= 0.f) ? MaxY[si] : MinY[si];
    out[e] = lrelu(sc * v + sh);
}

__global__ void mean_kernel(const float* __restrict__ xd1, const float* __restrict__ xd2,
                            float* __restrict__ hsum) {
    __shared__ float bins[128];
    const int tid = threadIdx.x;
    if (tid < 128) bins[tid] = 0.f;
    __syncthreads();
    const int half = BB * 64 * NN;
    const int stride = gridDim.x * 256;
    for (int e = blockIdx.x * 256 + tid; e < half; e += stride)
        atomicAdd(&bins[e & 127], xd1[e]);
    for (int e = blockIdx.x * 256 + tid; e < half; e += stride)
        atomicAdd(&bins[e & 127], xd2[e]);
    __syncthreads();
    if (tid < 128) atomicAdd(&hsum[tid], bins[tid]);
}

__global__ void head_kernel(const float* __restrict__ hsum,
                            const float* __restrict__ W2d, const float* __restrict__ b2d,
                            const float* __restrict__ W3d, const float* __restrict__ b3d,
                            const float* __restrict__ W4d, const float* __restrict__ b4d,
                            float* __restrict__ out) {
    __shared__ float h[128], t1[128], t2[64];
    const int t = threadIdx.x;
    h[t] = hsum[t] * (1.f / 32768.f);
    __syncthreads();
    float a = b2d[t];
    for (int j = 0; j < 128; j++) a += W2d[t * 128 + j] * h[j];
    t1[t] = lrelu(a);
    __syncthreads();
    if (t < 64) {
        float a2 = b3d[t];
        for (int j = 0; j < 128; j++) a2 += W3d[t * 128 + j] * t1[j];
        t2[t] = lrelu(a2);
    }
    __syncthreads();
    if (t < 11) {
        float a3 = b4d[t];
        for (int j = 0; j < 64; j++) a3 += W4d[t * 64 + j] * t2[j];
        out[t] = lrelu(a3);
    }
}

extern "C" void kernel_launch(void* const* d_in, const int* in_sizes, int n_in,
                              void* d_out, int out_size, void* d_ws, size_t ws_size,
                              hipStream_t stream) {
    const float* x   = (const float*)d_in[0];
    const float* w1  = (const float*)d_in[1];
    const float* g1  = (const float*)d_in[2];
    const float* b1  = (const float*)d_in[3];
    const float* w2  = (const float*)d_in[4];
    const float* g2  = (const float*)d_in[5];
    const float* b2  = (const float*)d_in[6];
    const float* wd1 = (const float*)d_in[7];
    const float* gd1 = (const float*)d_in[8];
    const float* bd1 = (const float*)d_in[9];
    const float* wd2 = (const float*)d_in[10];
    const float* gd2 = (const float*)d_in[11];
    const float* bd2 = (const float*)d_in[12];
    const float* W2d = (const float*)d_in[13];
    const float* b2d = (const float*)d_in[14];
    const float* W3d = (const float*)d_in[15];
    const float* b3d = (const float*)d_in[16];
    const float* W4d = (const float*)d_in[17];
    const float* b4d = (const float*)d_in[18];
    float* out = (float*)d_out;

    char* ws = (char*)d_ws;
    size_t off = 0;
    auto alloc = [&](size_t bytes) { char* p = ws + off; off += (bytes + 255) & ~size_t(255); return p; };
    int*   idx1  = (int*)  alloc(BB * NN * KK * 4);
    int*   idx2  = (int*)  alloc(BB * NN * KK * 4);
    int*   idx3  = (int*)  alloc(BB * NN * KK * 4);
    float* x1m   = (float*)alloc(BB * 32 * NN * 4);
    float* x2m   = (float*)alloc(BB * 64 * NN * 4);
    float* xd1   = (float*)alloc(BB * 64 * NN * 4);
    float* xd2   = (float*)alloc(BB * 64 * NN * 4);
    float* G1    = (float*)alloc((size_t)BB * NN * 64 * 4);
    float* G2    = (float*)alloc((size_t)BB * NN * 64 * 4);
    float* H     = (float*)alloc((size_t)BB * NN * 64 * 4);
    float* MaxY  = (float*)alloc((size_t)BB * NN * 64 * 4);
    float* MinY  = (float*)alloc((size_t)BB * NN * 64 * 4);
    float* stats = (float*)alloc(256 * 4);
    float* hsum  = (float*)alloc(128 * 4);
    float* hng   = (float*)alloc(BB * NN * 4);

    const float invP = 1.f / (float)(BB * NN * KK);
    const dim3 knn_grid(NN / 64, BB);
    const dim3 hn_grid(NN / 256, BB);

    zero_kernel<<<1, 256, 0, stream>>>(hsum, 128);

    // --- kNN on x (C=3) ---
    halfnorm_kernel<3><<<hn_grid, 256, 0, stream>>>(x, hng);
    knn_kernel<3><<<knn_grid, 256, 0, stream>>>(x, hng, idx1);

    // --- conv1: Cout=32, group (x, idx1, C=3), w1 CIN=6 ---
    zero_kernel<<<1, 256, 0, stream>>>(stats, 128);
    precompute_kernel<32><<<dim3(NN / 64, BB), dim3(32, 8), 2 * 3 * 32 * 4, stream>>>(
        x, 3, w1, 6, 0, 3, G1, H, 1, 1);
    conv_stats_kernel<32, 1><<<dim3(NN / 8, BB), dim3(32, 8), 0, stream>>>(
        G1, idx1, nullptr, nullptr, H, stats, MaxY, MinY);
    finalize_kernel<<<1, 64, 0, stream>>>(g1, b1, stats, 32, invP);
    apply_kernel<<<(BB * 32 * NN + 255) / 256, 256, 0, stream>>>(MaxY, MinY, stats, x1m, 32);

    // --- kNN on x1_max (C=32) ---
    halfnorm_kernel<32><<<hn_grid, 256, 0, stream>>>(x1m, hng);
    knn_kernel<32><<<knn_grid, 256, 0, stream>>>(x1m, hng, idx2);

    // --- conv2: Cout=64, groups (x, idx1, 3) + (x1m, idx2, 32), w2 CIN=70 ---
    zero_kernel<<<1, 256, 0, stream>>>(stats, 128);
    precompute_kernel<64><<<dim3(NN / 64, BB), dim3(64, 4), 2 * 3 * 64 * 4, stream>>>(
        x, 3, w2, 70, 0, 3, G1, H, 1, 1);
    precompute_kernel<64><<<dim3(NN / 64, BB), dim3(64, 4), 2 * 32 * 64 * 4, stream>>>(
        x1m, 32, w2, 70, 6, 38, G2, H, 1, 0);
    conv_stats_kernel<64, 2><<<dim3(NN / 4, BB), dim3(64, 4), 0, stream>>>(
        G1, idx1, G2, idx2, H, stats, MaxY, MinY);
    finalize_kernel<<<1, 64, 0, stream>>>(g2, b2, stats, 64, invP);
    apply_kernel<<<(BB * 64 * NN + 255) / 256, 256, 0, stream>>>(MaxY, MinY, stats, x2m, 64);

    // --- convd1: Cout=64, group (x1m, idx2, 32), wd1 CIN=64 ---
    zero_kernel<<<1, 256, 0, stream>>>(stats, 128);
    precompute_kernel<64><<<dim3(NN / 64, BB), dim3(64, 4), 2 * 32 * 64 * 4, stream>>>(
        x1m, 32, wd1, 64, 0, 32, G1, H, 1, 1);
    conv_stats_kernel<64, 1><<<dim3(NN / 4, BB), dim3(64, 4), 0, stream>>>(
        G1, idx2, nullptr, nullptr, H, stats, MaxY, MinY);
    finalize_kernel<<<1, 64, 0, stream>>>(gd1, bd1, stats, 64, invP);
    apply_kernel<<<(BB * 64 * NN + 255) / 256, 256, 0, stream>>>(MaxY, MinY, stats, xd1, 64);

    // --- kNN on x2_max (C=64) ---
    halfnorm_kernel<64><<<hn_grid, 256, 0, stream>>>(x2m, hng);
    knn_kernel<64><<<knn_grid, 256, 0, stream>>>(x2m, hng, idx3);

    // --- convd2: Cout=64, group (x2m, idx3, 64), wd2 CIN=128 ---
    zero_kernel<<<1, 256, 0, stream>>>(stats, 128);
    precompute_kernel<64><<<dim3(NN / 64, BB), dim3(64, 4), 2 * 64 * 64 * 4, stream>>>(
        x2m, 64, wd2, 128, 0, 64, G1, H, 1, 1);
    conv_stats_kernel<64, 1><<<dim3(NN / 4, BB), dim3(64, 4), 0, stream>>>(
        G1, idx3, nullptr, nullptr, H, stats, MaxY, MinY);
    finalize_kernel<<<1, 64, 0, stream>>>(gd2, bd2, stats, 64, invP);
    apply_kernel<<<(BB * 64 * NN + 255) / 256, 256, 0, stream>>>(MaxY, MinY, stats, xd2, 64);

    // --- global mean + MLP head ---
    mean_kernel<<<1024, 256, 0, stream>>>(xd1, xd2, hsum);
    head_kernel<<<1, 128, 0, stream>>>(hsum, W2d, b2d, W3d, b3d, W4d, b4d, out);
}